// Round 7
// baseline (34.317 us; speedup 1.0000x reference)
//
#include <hip/hip_runtime.h>

// NeRF volume rendering. R6 = R5 (DPP cross-lane, 8 samples/lane, 16 lanes/ray)
// + load-issue pinning: t+sigma issued at kernel top, c issued right after the
// sort, both pinned with sched_barrier(0) so the compiler cannot sink them
// (R3 showed plain hoisting gets undone). launch_bounds(256,8) keeps VGPR<=64
// (occupancy halves past 64 — the R4 regression mechanism).

#define DPP_QUAD_XOR1   0xB1   // quad_perm [1,0,3,2]
#define DPP_QUAD_XOR2   0x4E   // quad_perm [2,3,0,1]
#define DPP_QUAD_XOR3   0x1B   // quad_perm [3,2,1,0]
#define DPP_HALF_MIRROR 0x141  // xor7 within 16-lane row
#define DPP_ROW_MIRROR  0x140  // xor15 within 16-lane row
#define DPP_SHR1        0x111
#define DPP_SHR2        0x112
#define DPP_SHR4        0x114
#define DPP_SHR8        0x118
#define DPP_SHL1        0x101
#define DPP_SHL2        0x102
#define DPP_SHL4        0x104
#define DPP_SHL8        0x108

template <int CTRL>
__device__ __forceinline__ float dppf(float x) {
  return __int_as_float(__builtin_amdgcn_update_dpp(
      0, __float_as_int(x), CTRL, 0xF, 0xF, true));
}

#define CEX(a,b) { float mn_=fminf(v[a],v[b]); v[b]=fmaxf(v[a],v[b]); v[a]=mn_; }

#define CROSS_REV_DPP(CTRL, lowbit) { \
  float w_[8]; \
  _Pragma("unroll") for (int r_=0;r_<8;++r_) w_[r_]=dppf<CTRL>(v[7-r_]); \
  const bool lo_ = (gl & (lowbit)) == 0; \
  _Pragma("unroll") for (int r_=0;r_<8;++r_) \
    v[r_] = lo_ ? fminf(v[r_],w_[r_]) : fmaxf(v[r_],w_[r_]); }

#define CROSS_DPP(CTRL, lowbit) { \
  float w_[8]; \
  _Pragma("unroll") for (int r_=0;r_<8;++r_) w_[r_]=dppf<CTRL>(v[r_]); \
  const bool lo_ = (gl & (lowbit)) == 0; \
  _Pragma("unroll") for (int r_=0;r_<8;++r_) \
    v[r_] = lo_ ? fminf(v[r_],w_[r_]) : fmaxf(v[r_],w_[r_]); }

// xor4 has no DPP control — one pass stays on the DS pipe
#define CROSS_SWZ(mask, lowbit) { \
  float w_[8]; \
  _Pragma("unroll") for (int r_=0;r_<8;++r_) w_[r_]=__shfl_xor(v[r_], (mask)); \
  const bool lo_ = (gl & (lowbit)) == 0; \
  _Pragma("unroll") for (int r_=0;r_<8;++r_) \
    v[r_] = lo_ ? fminf(v[r_],w_[r_]) : fmaxf(v[r_],w_[r_]); }

#define INLANE8() { CEX(0,4) CEX(1,5) CEX(2,6) CEX(3,7) \
                    CEX(0,2) CEX(1,3) CEX(4,6) CEX(5,7) \
                    CEX(0,1) CEX(2,3) CEX(4,5) CEX(6,7) }

__global__ __launch_bounds__(256, 8) void nerf_render_kernel(
    const float* __restrict__ t,
    const float* __restrict__ sigma,
    const float* __restrict__ c,
    float* __restrict__ out,
    int n_rays) {
  const int tid  = threadIdx.x;
  const int lane = tid & 63;
  const int gl   = lane & 15;               // lane within the 16-lane ray group
  const int ray  = blockIdx.x * 16 + (tid >> 4);
  if (ray >= n_rays) return;

  // ---- issue t + sigma loads up front; pin them above the sort ----
  const float4* tb = (const float4*)(t     + (size_t)ray * 128 + gl * 8);
  const float4* sb = (const float4*)(sigma + (size_t)ray * 128 + gl * 8);
  const float4 tA = tb[0], tB = tb[1];
  const float4 sA = sb[0], sB = sb[1];
  __builtin_amdgcn_sched_barrier(0);   // loads may not sink below this point

  float v[8];
  v[0]=tA.x; v[1]=tA.y; v[2]=tA.z; v[3]=tA.w;
  v[4]=tB.x; v[5]=tB.y; v[6]=tB.z; v[7]=tB.w;

  // ---- in-lane Batcher odd-even mergesort of 8 (ascending, 19 CEs) ----
  CEX(0,1) CEX(2,3) CEX(4,5) CEX(6,7)
  CEX(0,2) CEX(1,3) CEX(4,6) CEX(5,7)
  CEX(1,2) CEX(5,6)
  CEX(0,4) CEX(1,5) CEX(2,6) CEX(3,7)
  CEX(2,4) CEX(3,5)
  CEX(1,2) CEX(3,4) CEX(5,6)

  // ---- merges 8->16 / 16->32 / 32->64 / 64->128 (DPP cross-lane) ----
  CROSS_REV_DPP(DPP_QUAD_XOR1, 1)  INLANE8()
  CROSS_REV_DPP(DPP_QUAD_XOR3, 2)  CROSS_DPP(DPP_QUAD_XOR1, 1)  INLANE8()
  CROSS_REV_DPP(DPP_HALF_MIRROR, 4) CROSS_DPP(DPP_QUAD_XOR2, 2)
    CROSS_DPP(DPP_QUAD_XOR1, 1)    INLANE8()
  CROSS_REV_DPP(DPP_ROW_MIRROR, 8)  CROSS_SWZ(4, 4)
    CROSS_DPP(DPP_QUAD_XOR2, 2)    CROSS_DPP(DPP_QUAD_XOR1, 1)  INLANE8()

  // ---- issue c loads now; dt/scan/exp (~250 cyc) hides their latency ----
  float carr[24];
  { const float4* cb = (const float4*)(c + (size_t)ray * 384 + gl * 24);
#pragma unroll
    for (int q = 0; q < 6; ++q) *(float4*)&carr[q * 4] = cb[q]; }
  __builtin_amdgcn_sched_barrier(0);   // c loads may not sink below this

  // ---- dt (last sample of ray gets dt = 0) ----
  const float nxt = dppf<DPP_SHL1>(v[0]);   // row-scoped: no cross-ray wrap
  float dt[8];
#pragma unroll
  for (int r = 0; r < 7; ++r) dt[r] = v[r + 1] - v[r];
  dt[7] = (gl == 15) ? 0.0f : (nxt - v[7]);

  // ---- sigma * dt ----
  float sdt[8];
  sdt[0]=sA.x*dt[0]; sdt[1]=sA.y*dt[1]; sdt[2]=sA.z*dt[2]; sdt[3]=sA.w*dt[3];
  sdt[4]=sB.x*dt[4]; sdt[5]=sB.y*dt[5]; sdt[6]=sB.z*dt[6]; sdt[7]=sB.w*dt[7];

  // ---- prefix sums: in-lane inclusive, then 16-lane scan via row_shr ----
  float p[8];
  p[0] = sdt[0];
#pragma unroll
  for (int r = 1; r < 8; ++r) p[r] = p[r - 1] + sdt[r];
  float s = p[7];
  s += dppf<DPP_SHR1>(s);
  s += dppf<DPP_SHR2>(s);
  s += dppf<DPP_SHR4>(s);
  s += dppf<DPP_SHR8>(s);
  const float excl = s - p[7];   // sum of all sdt before this lane's samples

  // ---- weights: wi_i = exp(-cum_excl_i) - exp(-cum_incl_i) ----
  float wi[8];
  float Eprev = __expf(-excl);
#pragma unroll
  for (int r = 0; r < 8; ++r) {
    const float Er = __expf(-(excl + p[r]));
    wi[r] = Eprev - Er;
    Eprev = Er;
  }

  // ---- color / depth partials ----
  float pr = 0.f, pg = 0.f, pb = 0.f, pd = 0.f;
#pragma unroll
  for (int r = 0; r < 8; ++r) {
    pr += wi[r] * carr[3 * r + 0];
    pg += wi[r] * carr[3 * r + 1];
    pb += wi[r] * carr[3 * r + 2];
    pd += wi[r] * v[r];
  }

  // ---- 16-lane down-shift reduction (result needed only at gl==0) ----
  pr += dppf<DPP_SHL8>(pr); pg += dppf<DPP_SHL8>(pg);
  pb += dppf<DPP_SHL8>(pb); pd += dppf<DPP_SHL8>(pd);
  pr += dppf<DPP_SHL4>(pr); pg += dppf<DPP_SHL4>(pg);
  pb += dppf<DPP_SHL4>(pb); pd += dppf<DPP_SHL4>(pd);
  pr += dppf<DPP_SHL2>(pr); pg += dppf<DPP_SHL2>(pg);
  pb += dppf<DPP_SHL2>(pb); pd += dppf<DPP_SHL2>(pd);
  pr += dppf<DPP_SHL1>(pr); pg += dppf<DPP_SHL1>(pg);
  pb += dppf<DPP_SHL1>(pb); pd += dppf<DPP_SHL1>(pd);

  // ---- stores: out = color [N*3] | depth [N] | wi [N*128] ----
  float* wo = out + (size_t)n_rays * 4 + (size_t)ray * 128 + gl * 8;
  *(float4*)(wo)     = make_float4(wi[0], wi[1], wi[2], wi[3]);
  *(float4*)(wo + 4) = make_float4(wi[4], wi[5], wi[6], wi[7]);
  if (gl == 0) {
    out[(size_t)ray * 3 + 0] = pr;
    out[(size_t)ray * 3 + 1] = pg;
    out[(size_t)ray * 3 + 2] = pb;
    out[(size_t)n_rays * 3 + ray] = pd;
  }
}

extern "C" void kernel_launch(void* const* d_in, const int* in_sizes, int n_in,
                              void* d_out, int out_size, void* d_ws, size_t ws_size,
                              hipStream_t stream) {
  const float* t     = (const float*)d_in[0];
  const float* sigma = (const float*)d_in[1];
  const float* c     = (const float*)d_in[2];
  float* out = (float*)d_out;
  const int n_rays = in_sizes[0] / 128;
  const int blocks = (n_rays + 15) / 16;   // 16 rays per 256-thread block
  nerf_render_kernel<<<blocks, 256, 0, stream>>>(t, sigma, c, out, n_rays);
}

// Round 8
// 33.027 us; speedup vs baseline: 1.0391x; 1.0391x over previous
//
#include <hip/hip_runtime.h>

// NeRF volume rendering. R7 = R5 (best: 33.1 us) — exact revert of R6.
// Structure: 8 samples/lane, 16 lanes/ray, 4 rays/wave; all cross-lane
// traffic on DPP (VALU) except one xor4 pass; bitonic sort with
// reversal-formulation merges so every CE is uniform-ascending min/max.
// R6's sched_barrier load-pinning regressed (compiler materialized loads
// late anyway); R3's NT stores regressed (forced writes past L3 to HBM).
// Effective L2-fill traffic 194 MB / 33.1 us = 5.9 TB/s = ~94% of the
// 6.29 TB/s measured fabric ceiling — at the memory roofline.

#define DPP_QUAD_XOR1   0xB1   // quad_perm [1,0,3,2]
#define DPP_QUAD_XOR2   0x4E   // quad_perm [2,3,0,1]
#define DPP_QUAD_XOR3   0x1B   // quad_perm [3,2,1,0]
#define DPP_HALF_MIRROR 0x141  // xor7 within 16-lane row
#define DPP_ROW_MIRROR  0x140  // xor15 within 16-lane row
#define DPP_SHR1        0x111
#define DPP_SHR2        0x112
#define DPP_SHR4        0x114
#define DPP_SHR8        0x118
#define DPP_SHL1        0x101
#define DPP_SHL2        0x102
#define DPP_SHL4        0x104
#define DPP_SHL8        0x108

template <int CTRL>
__device__ __forceinline__ float dppf(float x) {
  return __int_as_float(__builtin_amdgcn_update_dpp(
      0, __float_as_int(x), CTRL, 0xF, 0xF, true));
}

#define CEX(a,b) { float mn_=fminf(v[a],v[b]); v[b]=fmaxf(v[a],v[b]); v[a]=mn_; }

#define CROSS_REV_DPP(CTRL, lowbit) { \
  float w_[8]; \
  _Pragma("unroll") for (int r_=0;r_<8;++r_) w_[r_]=dppf<CTRL>(v[7-r_]); \
  const bool lo_ = (gl & (lowbit)) == 0; \
  _Pragma("unroll") for (int r_=0;r_<8;++r_) \
    v[r_] = lo_ ? fminf(v[r_],w_[r_]) : fmaxf(v[r_],w_[r_]); }

#define CROSS_DPP(CTRL, lowbit) { \
  float w_[8]; \
  _Pragma("unroll") for (int r_=0;r_<8;++r_) w_[r_]=dppf<CTRL>(v[r_]); \
  const bool lo_ = (gl & (lowbit)) == 0; \
  _Pragma("unroll") for (int r_=0;r_<8;++r_) \
    v[r_] = lo_ ? fminf(v[r_],w_[r_]) : fmaxf(v[r_],w_[r_]); }

// xor4 has no DPP control — one pass stays on the DS pipe
#define CROSS_SWZ(mask, lowbit) { \
  float w_[8]; \
  _Pragma("unroll") for (int r_=0;r_<8;++r_) w_[r_]=__shfl_xor(v[r_], (mask)); \
  const bool lo_ = (gl & (lowbit)) == 0; \
  _Pragma("unroll") for (int r_=0;r_<8;++r_) \
    v[r_] = lo_ ? fminf(v[r_],w_[r_]) : fmaxf(v[r_],w_[r_]); }

#define INLANE8() { CEX(0,4) CEX(1,5) CEX(2,6) CEX(3,7) \
                    CEX(0,2) CEX(1,3) CEX(4,6) CEX(5,7) \
                    CEX(0,1) CEX(2,3) CEX(4,5) CEX(6,7) }

__global__ __launch_bounds__(256) void nerf_render_kernel(
    const float* __restrict__ t,
    const float* __restrict__ sigma,
    const float* __restrict__ c,
    float* __restrict__ out,
    int n_rays) {
  const int tid  = threadIdx.x;
  const int lane = tid & 63;
  const int gl   = lane & 15;               // lane within the 16-lane ray group
  const int ray  = blockIdx.x * 16 + (tid >> 4);
  if (ray >= n_rays) return;

  // ---- load t: 8 contiguous samples per lane ----
  const float4* tb = (const float4*)(t + (size_t)ray * 128 + gl * 8);
  float v[8];
  { float4 a = tb[0], b = tb[1];
    v[0]=a.x; v[1]=a.y; v[2]=a.z; v[3]=a.w;
    v[4]=b.x; v[5]=b.y; v[6]=b.z; v[7]=b.w; }

  // ---- in-lane Batcher odd-even mergesort of 8 (ascending, 19 CEs) ----
  CEX(0,1) CEX(2,3) CEX(4,5) CEX(6,7)
  CEX(0,2) CEX(1,3) CEX(4,6) CEX(5,7)
  CEX(1,2) CEX(5,6)
  CEX(0,4) CEX(1,5) CEX(2,6) CEX(3,7)
  CEX(2,4) CEX(3,5)
  CEX(1,2) CEX(3,4) CEX(5,6)

  // ---- merges 8->16 / 16->32 / 32->64 / 64->128 (DPP cross-lane) ----
  CROSS_REV_DPP(DPP_QUAD_XOR1, 1)  INLANE8()
  CROSS_REV_DPP(DPP_QUAD_XOR3, 2)  CROSS_DPP(DPP_QUAD_XOR1, 1)  INLANE8()
  CROSS_REV_DPP(DPP_HALF_MIRROR, 4) CROSS_DPP(DPP_QUAD_XOR2, 2)
    CROSS_DPP(DPP_QUAD_XOR1, 1)    INLANE8()
  CROSS_REV_DPP(DPP_ROW_MIRROR, 8)  CROSS_SWZ(4, 4)
    CROSS_DPP(DPP_QUAD_XOR2, 2)    CROSS_DPP(DPP_QUAD_XOR1, 1)  INLANE8()

  // ---- dt (last sample of ray gets dt = 0) ----
  const float nxt = dppf<DPP_SHL1>(v[0]);   // row-scoped: no cross-ray wrap
  float dt[8];
#pragma unroll
  for (int r = 0; r < 7; ++r) dt[r] = v[r + 1] - v[r];
  dt[7] = (gl == 15) ? 0.0f : (nxt - v[7]);

  // ---- sigma * dt ----
  const float4* sb = (const float4*)(sigma + (size_t)ray * 128 + gl * 8);
  float sdt[8];
  { float4 a = sb[0], b = sb[1];
    sdt[0]=a.x*dt[0]; sdt[1]=a.y*dt[1]; sdt[2]=a.z*dt[2]; sdt[3]=a.w*dt[3];
    sdt[4]=b.x*dt[4]; sdt[5]=b.y*dt[5]; sdt[6]=b.z*dt[6]; sdt[7]=b.w*dt[7]; }

  // ---- prefix sums: in-lane inclusive, then 16-lane scan via row_shr ----
  float p[8];
  p[0] = sdt[0];
#pragma unroll
  for (int r = 1; r < 8; ++r) p[r] = p[r - 1] + sdt[r];
  float s = p[7];
  s += dppf<DPP_SHR1>(s);   // zero-fill == identity for add
  s += dppf<DPP_SHR2>(s);
  s += dppf<DPP_SHR4>(s);
  s += dppf<DPP_SHR8>(s);
  const float excl = s - p[7];   // sum of all sdt before this lane's samples

  // ---- weights: wi_i = exp(-cum_excl_i) - exp(-cum_incl_i) ----
  float wi[8];
  float Eprev = __expf(-excl);
#pragma unroll
  for (int r = 0; r < 8; ++r) {
    const float Er = __expf(-(excl + p[r]));
    wi[r] = Eprev - Er;
    Eprev = Er;
  }

  // ---- color / depth partials ----
  float carr[24];
  { const float4* cb = (const float4*)(c + (size_t)ray * 384 + gl * 24);
#pragma unroll
    for (int q = 0; q < 6; ++q) *(float4*)&carr[q * 4] = cb[q]; }
  float pr = 0.f, pg = 0.f, pb = 0.f, pd = 0.f;
#pragma unroll
  for (int r = 0; r < 8; ++r) {
    pr += wi[r] * carr[3 * r + 0];
    pg += wi[r] * carr[3 * r + 1];
    pb += wi[r] * carr[3 * r + 2];
    pd += wi[r] * v[r];
  }

  // ---- 16-lane down-shift reduction (result needed only at gl==0) ----
  pr += dppf<DPP_SHL8>(pr); pg += dppf<DPP_SHL8>(pg);
  pb += dppf<DPP_SHL8>(pb); pd += dppf<DPP_SHL8>(pd);
  pr += dppf<DPP_SHL4>(pr); pg += dppf<DPP_SHL4>(pg);
  pb += dppf<DPP_SHL4>(pb); pd += dppf<DPP_SHL4>(pd);
  pr += dppf<DPP_SHL2>(pr); pg += dppf<DPP_SHL2>(pg);
  pb += dppf<DPP_SHL2>(pb); pd += dppf<DPP_SHL2>(pd);
  pr += dppf<DPP_SHL1>(pr); pg += dppf<DPP_SHL1>(pg);
  pb += dppf<DPP_SHL1>(pb); pd += dppf<DPP_SHL1>(pd);

  // ---- stores: out = color [N*3] | depth [N] | wi [N*128] ----
  float* wo = out + (size_t)n_rays * 4 + (size_t)ray * 128 + gl * 8;
  *(float4*)(wo)     = make_float4(wi[0], wi[1], wi[2], wi[3]);
  *(float4*)(wo + 4) = make_float4(wi[4], wi[5], wi[6], wi[7]);
  if (gl == 0) {
    out[(size_t)ray * 3 + 0] = pr;
    out[(size_t)ray * 3 + 1] = pg;
    out[(size_t)ray * 3 + 2] = pb;
    out[(size_t)n_rays * 3 + ray] = pd;
  }
}

extern "C" void kernel_launch(void* const* d_in, const int* in_sizes, int n_in,
                              void* d_out, int out_size, void* d_ws, size_t ws_size,
                              hipStream_t stream) {
  const float* t     = (const float*)d_in[0];
  const float* sigma = (const float*)d_in[1];
  const float* c     = (const float*)d_in[2];
  float* out = (float*)d_out;
  const int n_rays = in_sizes[0] / 128;
  const int blocks = (n_rays + 15) / 16;   // 16 rays per 256-thread block
  nerf_render_kernel<<<blocks, 256, 0, stream>>>(t, sigma, c, out, n_rays);
}